// Round 8
// baseline (243.362 us; speedup 1.0000x reference)
//
#include <hip/hip_runtime.h>
#include <hip/hip_bf16.h>

typedef float f32x4 __attribute__((ext_vector_type(4)));
typedef short bf16x8 __attribute__((ext_vector_type(8)));
typedef unsigned short us8 __attribute__((ext_vector_type(8)));

__device__ __forceinline__ unsigned short f2bf(float f) {
  union { float f; unsigned u; } v; v.f = f;
  return (unsigned short)((v.u + 0x8000u) >> 16);   // round-half-up bf16
}
__device__ __forceinline__ float bf2f(unsigned short u) {
  union { unsigned u; float f; } v; v.u = ((unsigned)u) << 16;
  return v.f;
}

// ---------------------------------------------------------------------------
// Kernel 1: VmatT[b][n][p] (bf16), n = c*16+u*4+v (256), p = pi*64+pj (4096)
// ---------------------------------------------------------------------------
__global__ __launch_bounds__(256) void prep_vmat(const float* __restrict__ x,
                                                 unsigned short* __restrict__ vmatT) {
  int t = blockIdx.x * 256 + threadIdx.x;
  int pc = t & 511;
  int n  = (t >> 9) & 255;
  int b  = t >> 17;
  int c = n >> 4, u = (n >> 2) & 3, v = n & 3;
  int pi = pc >> 3;
  int pj0 = (pc & 7) << 3;
  int row = 2 * pi + u - 1;
  row = row < 0 ? 0 : (row > 127 ? 127 : row);
  const float* xr = x + ((size_t)(b * 16 + c) * 128 + row) * 128;
  us8 o;
#pragma unroll
  for (int e = 0; e < 8; ++e) {
    int col = 2 * (pj0 + e) + v - 1;
    col = col < 0 ? 0 : (col > 127 ? 127 : col);
    o[e] = f2bf(xr[col]);
  }
  *reinterpret_cast<us8*>(vmatT + (size_t)t * 8) = o;
}

// ---------------------------------------------------------------------------
// Kernel 2: A[b][q][n] (bf16) = sum_p scores[b][q][p] * VmatT[b][n][p]
// M=4096, N=256, K=4096. BQ=64, BK=64, 64 K-tiles. 4 waves as 2M x 2N:
// wave (wm,wn) owns q-rows wm*32..+31 (2 fragments) x n-cols wn*128..+127
// (8 fragments). Each bv ds_read feeds 2 MFMAs -> per-CU LDS-pipe time
// halves vs R7's pure M-split (was ~96% of the DRAM-floor iteration budget,
// co-saturating with HBM; now ~48%).
//  - A (scores, HBM): lane loads its 2 fragments direct from global
//    (rows wm*32+{0,16}+l15, k=l16*8). Reg-staged 2 tiles ahead (rE/rO,
//    8 f32x4 each); CONV extracts to fe/fo BEFORE the set is overwritten.
//  - B (VmatT, L2-resident): global_load_lds 16B, 1 tile ahead, ring-2
//    (2 x 32 KB); global source slot pre-swizzled gs = slot ^ (row&7);
//    reads apply the same XOR (2-way banks, free).
//  - per iter: CONV; issue B(kt+1) [8 vm]; issue A(kt+2) [8 vm]; MFMAs;
//    vmcnt(8) leaves A(kt+2) in flight across the single barrier.
//  - K-phase rotation (qbi&63) spreads DRAM column offsets across blocks.
//  - uniform 64 iters; tail prefetches wrap (&63), kept alive by trailing
//    asm so the vmcnt FIFO accounting stays exact.
// ---------------------------------------------------------------------------
__global__ __launch_bounds__(256, 2) void gemm_scores_vmat(
    const float* __restrict__ scores,
    const unsigned short* __restrict__ vmatT,
    unsigned short* __restrict__ Amat) {
  __shared__ unsigned short ldsB[2][16384];   // 256 rows x 64 bf16, x2

  int bid = blockIdx.x;
  int nb = ((bid & 7) << 6) | (bid >> 3);     // batch = XCD id
  int batch = nb >> 6;
  int qb = (nb & 63) << 6;
  const int phase = (bid >> 3) & 63;          // full-range K rotation

  const int t = threadIdx.x;
  const int lane = t & 63;
  const int wq = t >> 6;
  const int wm = wq >> 1, wn = wq & 1;        // 2M x 2N wave grid
  const int l15 = lane & 15, l16 = lane >> 4;

  // A: per-lane fragment base (rows = qb + wm*32 + {0,16} + l15, k = l16*8)
  const float* aLane =
      scores + ((size_t)(batch * 4096 + qb + wm * 32 + l15)) * 4096 + l16 * 8;
  const unsigned short* Vb = vmatT + (size_t)batch * 256 * 4096;

  // B staging: 8 chunks/thread; LDS dest linear, global source slot swizzled
  const unsigned short* bSrc[8];
  int bDst[8];
#pragma unroll
  for (int i = 0; i < 8; ++i) {
    int c = t + i * 256;
    int gs = (c & 7) ^ ((c >> 3) & 7);
    bSrc[i] = Vb + (size_t)(c >> 3) * 4096 + gs * 8;
    bDst[i] = c * 8;
  }
  const int pos0 = (l16 ^ (l15 & 7)) << 3;    // swizzled slot, ks=0 (elems)
  const int bRow = wn * 128 + l15;            // this wave's B row base (+ni*16)

  f32x4 acc[2][8];
#pragma unroll
  for (int m = 0; m < 2; ++m)
#pragma unroll
    for (int ni = 0; ni < 8; ++ni) acc[m][ni] = (f32x4){0.f, 0.f, 0.f, 0.f};

  f32x4 rE[8], rO[8];       // two named A reg sets: [m*4 + ks*2 + half]
  bf16x8 fe[2][2], fo[2][2];

#define SB __builtin_amdgcn_sched_barrier(0)
#define STAGE_B(kt, bufi)                                                     \
  {                                                                           \
    int kp_ = ((kt) + phase) & 63;                                            \
    _Pragma("unroll") for (int i = 0; i < 8; ++i)                             \
        __builtin_amdgcn_global_load_lds(                                     \
            (const __attribute__((address_space(1))) void*)(bSrc[i] + (size_t)kp_ * 64), \
            (__attribute__((address_space(3))) void*)&ldsB[bufi][bDst[i]],    \
            16, 0, 0);                                                        \
  }
#define LOAD_A(kt, rr)                                                        \
  {                                                                           \
    int kp_ = ((kt) + phase) & 63;                                            \
    const float* ap_ = aLane + (size_t)kp_ * 64;                              \
    rr[0] = *(const f32x4*)(ap_);                                             \
    rr[1] = *(const f32x4*)(ap_ + 4);                                         \
    rr[2] = *(const f32x4*)(ap_ + 32);                                        \
    rr[3] = *(const f32x4*)(ap_ + 36);                                        \
    const float* aq_ = ap_ + (size_t)16 * 4096;                               \
    rr[4] = *(const f32x4*)(aq_);                                             \
    rr[5] = *(const f32x4*)(aq_ + 4);                                         \
    rr[6] = *(const f32x4*)(aq_ + 32);                                        \
    rr[7] = *(const f32x4*)(aq_ + 36);                                        \
  }
#define CONV(rr, ff)                                                          \
  {                                                                           \
    _Pragma("unroll") for (int m = 0; m < 2; ++m)                             \
        _Pragma("unroll") for (int ks = 0; ks < 2; ++ks)                      \
            _Pragma("unroll") for (int e = 0; e < 4; ++e) {                   \
      ff[m][ks][e]     = (short)f2bf(rr[m * 4 + ks * 2][e]);                  \
      ff[m][ks][e + 4] = (short)f2bf(rr[m * 4 + ks * 2 + 1][e]);              \
    }                                                                         \
  }
#define MFMAS(ff, bufi)                                                       \
  {                                                                           \
    _Pragma("unroll") for (int ks = 0; ks < 2; ++ks)                          \
        _Pragma("unroll") for (int ni = 0; ni < 8; ++ni) {                    \
      bf16x8 bv = *(const bf16x8*)(&ldsB[bufi][0] +                           \
                                   (bRow + ni * 16) * 64 + (pos0 ^ (ks * 32))); \
      acc[0][ni] = __builtin_amdgcn_mfma_f32_16x16x32_bf16(ff[0][ks], bv,     \
                                                           acc[0][ni], 0, 0, 0); \
      acc[1][ni] = __builtin_amdgcn_mfma_f32_16x16x32_bf16(ff[1][ks], bv,     \
                                                           acc[1][ni], 0, 0, 0); \
    }                                                                         \
  }

  // ---- prologue: A(0)->rE, B(0)->buf0, A(1)->rO; keep A(1) in flight
  LOAD_A(0, rE);
  SB;
  STAGE_B(0, 0);
  SB;
  LOAD_A(1, rO);
  SB;
  asm volatile("s_waitcnt vmcnt(8)" ::: "memory");  // A0,B0 landed; A1 in flight
  SB;
  __builtin_amdgcn_s_barrier();
  SB;

  // ---- main loop: 64 uniform iters, unrolled x2 (static reg-set roles)
  for (int kt = 0; kt < 64; kt += 2) {
    // EVEN: consume rE=A(kt), buf0=B(kt)
    CONV(rE, fe);                // extract BEFORE reload
    SB;
    STAGE_B(kt + 1, 1);
    SB;
    LOAD_A(kt + 2, rE);
    SB;
    MFMAS(fe, 0);
    asm volatile("s_waitcnt vmcnt(8)" ::: "memory");  // A(kt+1),B(kt+1) landed
    SB;
    __builtin_amdgcn_s_barrier();
    SB;
    // ODD: consume rO=A(kt+1), buf1=B(kt+1)
    CONV(rO, fo);
    SB;
    STAGE_B(kt + 2, 0);
    SB;
    LOAD_A(kt + 3, rO);
    SB;
    MFMAS(fo, 1);
    asm volatile("s_waitcnt vmcnt(8)" ::: "memory");
    SB;
    __builtin_amdgcn_s_barrier();
    SB;
  }

  // keep tail prefetches live so the loop's vmcnt FIFO accounting is exact
  asm volatile("" ::"v"(rE[0][0]), "v"(rE[1][0]), "v"(rE[2][0]), "v"(rE[3][0]),
               "v"(rE[4][0]), "v"(rE[5][0]), "v"(rE[6][0]), "v"(rE[7][0]),
               "v"(rO[0][0]), "v"(rO[1][0]), "v"(rO[2][0]), "v"(rO[3][0]),
               "v"(rO[4][0]), "v"(rO[5][0]), "v"(rO[6][0]), "v"(rO[7][0]));

#undef SB
#undef STAGE_B
#undef LOAD_A
#undef CONV
#undef MFMAS

  // C-write: wave (wm,wn): rows qb+wm*32+m*16+l16*4+j, col wn*128+ni*16+l15
  unsigned short* Ao =
      Amat + ((size_t)(batch * 4096 + qb + wm * 32)) * 256 + wn * 128;
#pragma unroll
  for (int m = 0; m < 2; ++m)
#pragma unroll
    for (int ni = 0; ni < 8; ++ni)
#pragma unroll
      for (int j = 0; j < 4; ++j)
        Ao[(size_t)(m * 16 + l16 * 4 + j) * 256 + ni * 16 + l15] =
            f2bf(acc[m][ni][j]);
}

// ---------------------------------------------------------------------------
// Kernel 3: out = x + alpha/4 * gathered conv_transpose contributions
// ---------------------------------------------------------------------------
__global__ __launch_bounds__(256) void epilogue_kernel(
    const float* __restrict__ x, const unsigned short* __restrict__ Amat,
    const float* __restrict__ alpha, float* __restrict__ out) {
  int b = blockIdx.x >> 7;
  int h = blockIdx.x & 127;
  int t = threadIdx.x;
  int w = t & 127;
  int cg = t >> 7;

  int ihi = (h + 1) >> 1, u_hi = (h + 1) & 1;
  int jhi = (w + 1) >> 1, v_hi = (w + 1) & 1;
  bool vi_hi = (ihi <= 63), vi_lo = (ihi >= 1);
  bool vj_hi = (jhi <= 63), vj_lo = (jhi >= 1);

  float al = alpha[0] * 0.25f;
  const unsigned short* Ab = Amat + (size_t)b * 4096 * 256;

#pragma unroll
  for (int cc = 0; cc < 8; ++cc) {
    int c = cg * 8 + cc;
    float s = 0.f;
    if (vi_hi) {
      const unsigned short* Ar = Ab + (size_t)(ihi * 64) * 256 + c * 16 + u_hi * 4;
      if (vj_hi) s += bf2f(Ar[jhi * 256 + v_hi]);
      if (vj_lo) s += bf2f(Ar[(jhi - 1) * 256 + v_hi + 2]);
    }
    if (vi_lo) {
      const unsigned short* Ar = Ab + (size_t)((ihi - 1) * 64) * 256 + c * 16 + (u_hi + 2) * 4;
      if (vj_hi) s += bf2f(Ar[jhi * 256 + v_hi]);
      if (vj_lo) s += bf2f(Ar[(jhi - 1) * 256 + v_hi + 2]);
    }
    size_t xi = (((size_t)b * 16 + c) * 128 + h) * 128 + w;
    out[xi] = x[xi] + al * s;
  }
}

extern "C" void kernel_launch(void* const* d_in, const int* in_sizes, int n_in,
                              void* d_out, int out_size, void* d_ws, size_t ws_size,
                              hipStream_t stream) {
  const float* x      = (const float*)d_in[0];
  const float* scores = (const float*)d_in[1];
  const float* alpha  = (const float*)d_in[2];
  float* out = (float*)d_out;

  unsigned short* vmatT = (unsigned short*)d_ws;
  unsigned short* Amat  = (unsigned short*)((char*)d_ws + (size_t)16 * 1024 * 1024);

  prep_vmat<<<4096, 256, 0, stream>>>(x, vmatT);
  gemm_scores_vmat<<<512, 256, 0, stream>>>(scores, vmatT, Amat);
  epilogue_kernel<<<1024, 256, 0, stream>>>(x, Amat, alpha, out);
}

// Round 9
// 193.466 us; speedup vs baseline: 1.2579x; 1.2579x over previous
//
#include <hip/hip_runtime.h>
#include <hip/hip_bf16.h>

typedef float f32x4 __attribute__((ext_vector_type(4)));
typedef short bf16x8 __attribute__((ext_vector_type(8)));
typedef unsigned short us8 __attribute__((ext_vector_type(8)));

__device__ __forceinline__ unsigned short f2bf(float f) {
  union { float f; unsigned u; } v; v.f = f;
  return (unsigned short)((v.u + 0x8000u) >> 16);   // round-half-up bf16
}
__device__ __forceinline__ float bf2f(unsigned short u) {
  union { unsigned u; float f; } v; v.u = ((unsigned)u) << 16;
  return v.f;
}

// ---------------------------------------------------------------------------
// Kernel 1: VmatT[b][n][p] (bf16), n = c*16+u*4+v (256), p = pi*64+pj (4096)
// ---------------------------------------------------------------------------
__global__ __launch_bounds__(256) void prep_vmat(const float* __restrict__ x,
                                                 unsigned short* __restrict__ vmatT) {
  int t = blockIdx.x * 256 + threadIdx.x;
  int pc = t & 511;
  int n  = (t >> 9) & 255;
  int b  = t >> 17;
  int c = n >> 4, u = (n >> 2) & 3, v = n & 3;
  int pi = pc >> 3;
  int pj0 = (pc & 7) << 3;
  int row = 2 * pi + u - 1;
  row = row < 0 ? 0 : (row > 127 ? 127 : row);
  const float* xr = x + ((size_t)(b * 16 + c) * 128 + row) * 128;
  us8 o;
#pragma unroll
  for (int e = 0; e < 8; ++e) {
    int col = 2 * (pj0 + e) + v - 1;
    col = col < 0 ? 0 : (col > 127 ? 127 : col);
    o[e] = f2bf(xr[col]);
  }
  *reinterpret_cast<us8*>(vmatT + (size_t)t * 8) = o;
}

// ---------------------------------------------------------------------------
// Kernel 2: A[b][q][n] (bf16) = sum_p scores[b][q][p] * VmatT[b][n][p]
// R7 structure (M-split, BQ=64, BK=64, 64 tiles, B ring-2 in 64 KB LDS)
// with two A-stream fixes:
//  - PAIRED A loads: tiles {k,k+1} fetched as ONE 512-B-per-row burst
//    (8 x dwordx4 per lane) once per 2 iters, into alternating rP/rQ sets.
//    Even iter: vmcnt(8) keeps the new pair in flight across the barrier
//    (~1.3 iters of cover); odd iter: vmcnt(0) (pair had ~4000 cyc to land;
//    B(k0+2) covered by the MFMA phase, as in R7).
//  - NONTEMPORAL scores loads (nt): the 512-MB single-use stream stops
//    evicting the 2-MB VmatT slice from the XCD L2.
// phase rotation kept, forced EVEN so pairs stay k-contiguous.
// ---------------------------------------------------------------------------
__global__ __launch_bounds__(256) void gemm_scores_vmat(
    const float* __restrict__ scores,
    const unsigned short* __restrict__ vmatT,
    unsigned short* __restrict__ Amat) {
  __shared__ unsigned short ldsB[2][16384];   // 256 rows x 64 bf16, x2

  int bid = blockIdx.x;
  int nb = ((bid & 7) << 6) | (bid >> 3);     // batch = XCD id
  int batch = nb >> 6;
  int qb = (nb & 63) << 6;
  const int phase = ((bid >> 3) & 31) * 2;    // even K rotation (pair-aligned)

  const int t = threadIdx.x;
  const int lane = t & 63;
  const int wq = t >> 6;                      // wave id = M-quadrant
  const int l15 = lane & 15, l16 = lane >> 4;

  // A: per-lane fragment base (row = qb + wq*16 + l15, k-offset l16*8)
  const float* aLane =
      scores + ((size_t)(batch * 4096 + qb + wq * 16 + l15)) * 4096 + l16 * 8;
  const unsigned short* Vb = vmatT + (size_t)batch * 256 * 4096;

  // B staging: 8 chunks/thread; LDS dest linear, global source slot swizzled
  const unsigned short* bSrc[8];
  int bDst[8];
#pragma unroll
  for (int i = 0; i < 8; ++i) {
    int c = t + i * 256;
    int gs = (c & 7) ^ ((c >> 3) & 7);
    bSrc[i] = Vb + (size_t)(c >> 3) * 4096 + gs * 8;
    bDst[i] = c * 8;
  }
  const int pos0 = (l16 ^ (l15 & 7)) << 3;    // swizzled slot, ks=0 (elems)

  f32x4 acc[16];
#pragma unroll
  for (int ni = 0; ni < 16; ++ni) acc[ni] = (f32x4){0.f, 0.f, 0.f, 0.f};

  f32x4 rP[8], rQ[8];     // alternating A pair-sets (tiles {k,k+1}), static
  bf16x8 fe0, fe1, fo0, fo1;

#define SB __builtin_amdgcn_sched_barrier(0)
#define STAGE_B(kt, bufi)                                                     \
  {                                                                           \
    int kp_ = ((kt) + phase) & 63;                                            \
    _Pragma("unroll") for (int i = 0; i < 8; ++i)                             \
        __builtin_amdgcn_global_load_lds(                                     \
            (const __attribute__((address_space(1))) void*)(bSrc[i] + (size_t)kp_ * 64), \
            (__attribute__((address_space(3))) void*)&ldsB[bufi][bDst[i]],    \
            16, 0, 0);                                                        \
  }
// paired A load: tiles {kt, kt+1} (kt even, phase even -> no wrap inside)
#define LOAD_A2(kt, rr)                                                       \
  {                                                                           \
    int kp_ = ((kt) + phase) & 63;                                            \
    const float* ap_ = aLane + (size_t)kp_ * 64;                              \
    rr[0] = __builtin_nontemporal_load((const f32x4*)(ap_));                  \
    rr[1] = __builtin_nontemporal_load((const f32x4*)(ap_ + 4));              \
    rr[2] = __builtin_nontemporal_load((const f32x4*)(ap_ + 32));             \
    rr[3] = __builtin_nontemporal_load((const f32x4*)(ap_ + 36));             \
    rr[4] = __builtin_nontemporal_load((const f32x4*)(ap_ + 64));             \
    rr[5] = __builtin_nontemporal_load((const f32x4*)(ap_ + 68));             \
    rr[6] = __builtin_nontemporal_load((const f32x4*)(ap_ + 96));             \
    rr[7] = __builtin_nontemporal_load((const f32x4*)(ap_ + 100));            \
  }
#define CONV4(r0_, r1_, fa0, fa1)                                             \
  {                                                                           \
    _Pragma("unroll") for (int e = 0; e < 4; ++e) {                           \
      fa0[e]     = (short)f2bf(r0_[e]);                                       \
      fa0[e + 4] = (short)f2bf(r1_[e]);                                       \
    }                                                                         \
    _Pragma("unroll") for (int e = 0; e < 4; ++e) {                           \
      fa1[e]     = (short)f2bf((&r0_)[2][e]);                                 \
      fa1[e + 4] = (short)f2bf((&r0_)[3][e]);                                 \
    }                                                                         \
  }
#define MFMAS(fa0, fa1, bufi)                                                 \
  {                                                                           \
    _Pragma("unroll") for (int ni = 0; ni < 16; ++ni) {                       \
      bf16x8 bv = *(const bf16x8*)(&ldsB[bufi][0] +                           \
                                   (ni * 16 + l15) * 64 + pos0);              \
      acc[ni] = __builtin_amdgcn_mfma_f32_16x16x32_bf16(fa0, bv, acc[ni],     \
                                                        0, 0, 0);             \
    }                                                                         \
    _Pragma("unroll") for (int ni = 0; ni < 16; ++ni) {                       \
      bf16x8 bv = *(const bf16x8*)(&ldsB[bufi][0] +                           \
                                   (ni * 16 + l15) * 64 + (pos0 ^ 32));      \
      acc[ni] = __builtin_amdgcn_mfma_f32_16x16x32_bf16(fa1, bv, acc[ni],     \
                                                        0, 0, 0);             \
    }                                                                         \
  }
// one pair: tiles {k0, k0+1}; consumes `cons`, loads NEXT pair into `load`
#define PAIR(cons, load, k0)                                                  \
  {                                                                           \
    /* EVEN: tile k0, buf0 */                                                 \
    CONV4(cons[0], cons[1], fe0, fe1);                                        \
    SB;                                                                       \
    STAGE_B((k0) + 1, 1);                                                     \
    SB;                                                                       \
    LOAD_A2((k0) + 2, load);                                                  \
    SB;                                                                       \
    MFMAS(fe0, fe1, 0);                                                       \
    asm volatile("s_waitcnt vmcnt(8)" ::: "memory");  /* B landed; pair rides */ \
    SB;                                                                       \
    __builtin_amdgcn_s_barrier();                                             \
    SB;                                                                       \
    /* ODD: tile k0+1, buf1 */                                                \
    CONV4(cons[4], cons[5], fo0, fo1);                                        \
    SB;                                                                       \
    STAGE_B((k0) + 2, 0);                                                     \
    SB;                                                                       \
    MFMAS(fo0, fo1, 1);                                                       \
    asm volatile("s_waitcnt vmcnt(0)" ::: "memory");  /* pair + B drained */  \
    SB;                                                                       \
    __builtin_amdgcn_s_barrier();                                             \
    SB;                                                                       \
  }

  // ---- prologue: pair {0,1} -> rP, B(0) -> buf0
  LOAD_A2(0, rP);
  SB;
  STAGE_B(0, 0);
  SB;
  asm volatile("s_waitcnt vmcnt(0)" ::: "memory");
  SB;
  __builtin_amdgcn_s_barrier();
  SB;

  // ---- main loop: 32 pairs, roles alternate -> unroll 2 pairs per body
  for (int j = 0; j < 32; j += 2) {
    PAIR(rP, rQ, 2 * j);
    PAIR(rQ, rP, 2 * j + 2);
  }

  // keep tail dummy loads live so the vmcnt FIFO accounting stays exact
  asm volatile("" ::"v"(rP[0][0]), "v"(rP[4][0]), "v"(rQ[0][0]), "v"(rQ[4][0]));

#undef SB
#undef STAGE_B
#undef LOAD_A2
#undef CONV4
#undef MFMAS
#undef PAIR

  // C-write: wave wq owns q-rows qb+wq*16..+15; row=(l16*4+j), col=l15 per ni
  unsigned short* Ao = Amat + ((size_t)(batch * 4096 + qb + wq * 16)) * 256;
#pragma unroll
  for (int ni = 0; ni < 16; ++ni)
#pragma unroll
    for (int j = 0; j < 4; ++j)
      Ao[(size_t)(l16 * 4 + j) * 256 + ni * 16 + l15] = f2bf(acc[ni][j]);
}

// ---------------------------------------------------------------------------
// Kernel 3: out = x + alpha/4 * gathered conv_transpose contributions
// ---------------------------------------------------------------------------
__global__ __launch_bounds__(256) void epilogue_kernel(
    const float* __restrict__ x, const unsigned short* __restrict__ Amat,
    const float* __restrict__ alpha, float* __restrict__ out) {
  int b = blockIdx.x >> 7;
  int h = blockIdx.x & 127;
  int t = threadIdx.x;
  int w = t & 127;
  int cg = t >> 7;

  int ihi = (h + 1) >> 1, u_hi = (h + 1) & 1;
  int jhi = (w + 1) >> 1, v_hi = (w + 1) & 1;
  bool vi_hi = (ihi <= 63), vi_lo = (ihi >= 1);
  bool vj_hi = (jhi <= 63), vj_lo = (jhi >= 1);

  float al = alpha[0] * 0.25f;
  const unsigned short* Ab = Amat + (size_t)b * 4096 * 256;

#pragma unroll
  for (int cc = 0; cc < 8; ++cc) {
    int c = cg * 8 + cc;
    float s = 0.f;
    if (vi_hi) {
      const unsigned short* Ar = Ab + (size_t)(ihi * 64) * 256 + c * 16 + u_hi * 4;
      if (vj_hi) s += bf2f(Ar[jhi * 256 + v_hi]);
      if (vj_lo) s += bf2f(Ar[(jhi - 1) * 256 + v_hi + 2]);
    }
    if (vi_lo) {
      const unsigned short* Ar = Ab + (size_t)((ihi - 1) * 64) * 256 + c * 16 + (u_hi + 2) * 4;
      if (vj_hi) s += bf2f(Ar[jhi * 256 + v_hi]);
      if (vj_lo) s += bf2f(Ar[(jhi - 1) * 256 + v_hi + 2]);
    }
    size_t xi = (((size_t)b * 16 + c) * 128 + h) * 128 + w;
    out[xi] = x[xi] + al * s;
  }
}

extern "C" void kernel_launch(void* const* d_in, const int* in_sizes, int n_in,
                              void* d_out, int out_size, void* d_ws, size_t ws_size,
                              hipStream_t stream) {
  const float* x      = (const float*)d_in[0];
  const float* scores = (const float*)d_in[1];
  const float* alpha  = (const float*)d_in[2];
  float* out = (float*)d_out;

  unsigned short* vmatT = (unsigned short*)d_ws;
  unsigned short* Amat  = (unsigned short*)((char*)d_ws + (size_t)16 * 1024 * 1024);

  prep_vmat<<<4096, 256, 0, stream>>>(x, vmatT);
  gemm_scores_vmat<<<512, 256, 0, stream>>>(scores, vmatT, Amat);
  epilogue_kernel<<<1024, 256, 0, stream>>>(x, Amat, alpha, out);
}